// Round 1
// 3516.291 us; speedup vs baseline: 1.7289x; 1.7289x over previous
//
#include <hip/hip_runtime.h>
#include <math.h>

// ---- problem constants ----
static constexpr int Bc   = 4;
static constexpr int Sc   = 512;
static constexpr int Dc   = 512;     // d_model
static constexpr int Hc   = 8;
static constexpr int DKc  = 64;
static constexpr int NXc  = 6;
static constexpr int DFFc = 2048;
static constexpr int Vc   = 37000;
static constexpr int Mc   = Bc * Sc; // 2048 rows
static constexpr float BN_EPS = 1e-5f;

#define NEG_INF (-1e30f)

// ---- MFMA types / helpers ----
using bf16x8 = __attribute__((ext_vector_type(8))) short;
using f32x4  = __attribute__((ext_vector_type(4))) float;

__device__ inline unsigned short f2bf(float f) {
  union { float f; unsigned u; } v; v.f = f;
  unsigned r = v.u + 0x7FFFu + ((v.u >> 16) & 1u);   // RNE
  return (unsigned short)(r >> 16);
}

__device__ inline float f4get(const float4& v, int j) {
  return j == 0 ? v.x : (j == 1 ? v.y : (j == 2 ? v.z : v.w));
}

__device__ inline bf16x8 cvt8(float4 a, float4 b) {
  union { bf16x8 v; unsigned short s[8]; } u;
  u.s[0] = f2bf(a.x); u.s[1] = f2bf(a.y); u.s[2] = f2bf(a.z); u.s[3] = f2bf(a.w);
  u.s[4] = f2bf(b.x); u.s[5] = f2bf(b.y); u.s[6] = f2bf(b.z); u.s[7] = f2bf(b.w);
  return u.v;
}

// ---------------- elementwise ----------------
__global__ void embed_k(const int* __restrict__ idx, const float* __restrict__ emb,
                        float* __restrict__ x) {
  int i = blockIdx.x * blockDim.x + threadIdx.x;
  if (i >= Mc * Dc) return;
  int r = i >> 9;          // / 512
  int d = i & 511;
  x[i] = emb[(long)idx[r] * Dc + d] * 8.0f;   // * sqrt(d_k)=8
}

__global__ void add_k(float* __restrict__ x, const float* __restrict__ y, int n) {
  int i = blockIdx.x * blockDim.x + threadIdx.x;
  if (i < n) x[i] += y[i];
}

// O[b,h,s,e] -> cc[b*S+s, h*64+e]
__global__ void concat_k(const float* __restrict__ O, float* __restrict__ out) {
  int i = blockIdx.x * blockDim.x + threadIdx.x;
  if (i >= Mc * Dc) return;
  int r = i >> 9, c = i & 511;
  int b = r >> 9, s = r & 511;
  int h = c >> 6, e = c & 63;
  out[i] = O[((((long)b * Hc + h) * Sc + s) << 6) + e];
}

// ---------------- bf16-MFMA GEMM NN: C = alpha*A@B (+bias)(+relu) ------------
// Block tile 128x128, BK=32, 256 threads = 4 waves (2x2), 64x64 per wave.
// fp32 in / fp32 out; converts to bf16 while staging into LDS.
// mode==0: A = A + z*aB, B = B0 + z*bB
// mode==2: fused QKV. z = t*32 + zz (t: 0=Q,1=K,2=V); A-source = (t==0 ? A : A2)
//          + (zz/H)*aB; B-source = {B0,B1,B2}[t] + (zz%H)*bB; C += z*cB, with
//          Q/K/V output buffers contiguous so z*cB spans all three.
static constexpr int GLDA = 40;   // padded LDS row (ushorts): 80B keeps 16B align, spreads banks

__global__ __launch_bounds__(256) void gemm_nn_mfma(
    const float* __restrict__ A, const float* __restrict__ A2,
    const float* __restrict__ B0, const float* __restrict__ B1, const float* __restrict__ B2,
    const float* __restrict__ bias, float* __restrict__ C,
    int M, int N, int K, long aB, long bB, long cB, int mode,
    float alpha, int relu)
{
  int z = blockIdx.z;
  const float* Ap;
  const float* Bp;
  if (mode == 2) {
    int t = z >> 5, zz = z & 31;
    Ap = (t == 0 ? A : A2) + (long)(zz >> 3) * aB;
    Bp = (t == 0 ? B0 : (t == 1 ? B1 : B2)) + (long)(zz & 7) * bB;
  } else {
    Ap = A  + (long)z * aB;
    Bp = B0 + (long)z * bB;
  }
  C += (long)z * cB;

  __shared__ unsigned short sA[128 * GLDA];  // [m][k]
  __shared__ unsigned short sB[128 * GLDA];  // [n][k] (B stored transposed)

  int tid  = threadIdx.x;
  int lane = tid & 63;
  int wave = tid >> 6;
  int row0 = blockIdx.x * 128, col0 = blockIdx.y * 128;

  float4 ra[4], rb[4];
  int arow = tid >> 3, acol = (tid & 7) * 4;      // A staging: 4 passes of 32 rows
  int nb = (tid & 31) * 4, kb = (tid >> 5) * 4;   // B staging: 4 cols x 4 ks per thread

  auto load_tiles = [&](int k0) {
#pragma unroll
    for (int p = 0; p < 4; p++)
      ra[p] = *(const float4*)(Ap + (long)(row0 + arow + p * 32) * K + k0 + acol);
    bool ok = (col0 + nb + 4 <= N);
#pragma unroll
    for (int i = 0; i < 4; i++)
      rb[i] = ok ? *(const float4*)(Bp + (long)(k0 + kb + i) * N + col0 + nb)
                 : make_float4(0.f, 0.f, 0.f, 0.f);
  };

  f32x4 zero4 = {0.f, 0.f, 0.f, 0.f};
  f32x4 acc[4][4];
#pragma unroll
  for (int i = 0; i < 4; i++)
#pragma unroll
    for (int j = 0; j < 4; j++) acc[i][j] = zero4;

  int m0 = (wave >> 1) * 64, n0 = (wave & 1) * 64;
  int fr = lane & 15, fk = (lane >> 4) * 8;

  load_tiles(0);
  for (int k0 = 0; ; ) {
    __syncthreads();   // previous iteration's LDS readers done
    // stage A (convert to bf16)
#pragma unroll
    for (int p = 0; p < 4; p++) {
      unsigned w0 = (unsigned)f2bf(ra[p].x) | ((unsigned)f2bf(ra[p].y) << 16);
      unsigned w1 = (unsigned)f2bf(ra[p].z) | ((unsigned)f2bf(ra[p].w) << 16);
      unsigned* dst = (unsigned*)&sA[(arow + p * 32) * GLDA + acol];
      dst[0] = w0; dst[1] = w1;
    }
    // stage B transposed [n][k]
#pragma unroll
    for (int j = 0; j < 4; j++) {
      unsigned w0 = (unsigned)f2bf(f4get(rb[0], j)) | ((unsigned)f2bf(f4get(rb[1], j)) << 16);
      unsigned w1 = (unsigned)f2bf(f4get(rb[2], j)) | ((unsigned)f2bf(f4get(rb[3], j)) << 16);
      unsigned* dst = (unsigned*)&sB[(nb + j) * GLDA + kb];
      dst[0] = w0; dst[1] = w1;
    }
    __syncthreads();

    int kn = k0 + 32;
    bool more = kn < K;
    if (more) load_tiles(kn);   // prefetch next tile under the MFMA phase

    bf16x8 af[4], bfr[4];
#pragma unroll
    for (int i = 0; i < 4; i++) {
      af[i]  = *(const bf16x8*)&sA[(m0 + i * 16 + fr) * GLDA + fk];
      bfr[i] = *(const bf16x8*)&sB[(n0 + i * 16 + fr) * GLDA + fk];
    }
#pragma unroll
    for (int mi = 0; mi < 4; mi++)
#pragma unroll
      for (int ni = 0; ni < 4; ni++)
        acc[mi][ni] = __builtin_amdgcn_mfma_f32_16x16x32_bf16(af[mi], bfr[ni], acc[mi][ni], 0, 0, 0);

    if (!more) break;
    k0 = kn;
  }

  // epilogue: C/D layout col=lane&15, row=(lane>>4)*4+j  [m89-verified]
  int rg = (lane >> 4) << 2;
#pragma unroll
  for (int ni = 0; ni < 4; ni++) {
    int col = col0 + n0 + ni * 16 + fr;
    if (col < N) {
      float bv = bias ? bias[col] : 0.f;
#pragma unroll
      for (int mi = 0; mi < 4; mi++) {
        int r0 = row0 + m0 + mi * 16 + rg;
#pragma unroll
        for (int j = 0; j < 4; j++) {
          float o = acc[mi][ni][j] * alpha + bv;
          if (relu) o = fmaxf(o, 0.f);
          C[(long)(r0 + j) * N + col] = o;
        }
      }
    }
  }
}

// ---------------- bf16-MFMA GEMM NT: scores = alpha * Q @ K^T ----------------
// M=N=512, K=64 fixed. Both operands k-contiguous row-major -> fragments load
// straight from global (L2-hot), no LDS. Causal: skip fully-masked tiles.
__global__ __launch_bounds__(256) void gemm_nt_mfma(
    const float* __restrict__ A, const float* __restrict__ Bm, float* __restrict__ C,
    long aB, long bB, long cB, float alpha, int causal)
{
  if (causal && blockIdx.y > blockIdx.x) return;   // tile entirely above diagonal
  int z = blockIdx.z;
  const float* Ap = A  + (long)z * aB;
  const float* Bp = Bm + (long)z * bB;
  float* Cp = C + (long)z * cB;

  int tid = threadIdx.x, lane = tid & 63, wave = tid >> 6;
  int m0 = blockIdx.x * 128 + (wave >> 1) * 64;
  int n0 = blockIdx.y * 128 + (wave & 1) * 64;
  int fr = lane & 15, fk = (lane >> 4) * 8;

  bf16x8 af[4][2];
#pragma unroll
  for (int mi = 0; mi < 4; mi++) {
    const float* p = Ap + (long)(m0 + mi * 16 + fr) * DKc + fk;
    af[mi][0] = cvt8(*(const float4*)p,        *(const float4*)(p + 4));
    af[mi][1] = cvt8(*(const float4*)(p + 32), *(const float4*)(p + 36));
  }

  f32x4 zero4 = {0.f, 0.f, 0.f, 0.f};
  f32x4 acc[4][4];
#pragma unroll
  for (int i = 0; i < 4; i++)
#pragma unroll
    for (int j = 0; j < 4; j++) acc[i][j] = zero4;

#pragma unroll
  for (int ni = 0; ni < 4; ni++) {
    const float* q = Bp + (long)(n0 + ni * 16 + fr) * DKc + fk;
    bf16x8 b0 = cvt8(*(const float4*)q,        *(const float4*)(q + 4));
    bf16x8 b1 = cvt8(*(const float4*)(q + 32), *(const float4*)(q + 36));
#pragma unroll
    for (int mi = 0; mi < 4; mi++) {
      acc[mi][ni] = __builtin_amdgcn_mfma_f32_16x16x32_bf16(af[mi][0], b0, acc[mi][ni], 0, 0, 0);
      acc[mi][ni] = __builtin_amdgcn_mfma_f32_16x16x32_bf16(af[mi][1], b1, acc[mi][ni], 0, 0, 0);
    }
  }

  int rg = (lane >> 4) << 2;
#pragma unroll
  for (int ni = 0; ni < 4; ni++) {
    int col = n0 + ni * 16 + fr;
#pragma unroll
    for (int mi = 0; mi < 4; mi++) {
      int r0 = m0 + mi * 16 + rg;
#pragma unroll
      for (int j = 0; j < 4; j++)
        Cp[(long)(r0 + j) * Sc + col] = acc[mi][ni][j] * alpha;
    }
  }
}

// ---------------- attention softmax (row of 512, causal mask optional) ----
__global__ __launch_bounds__(256) void attn_softmax(float* __restrict__ sc, int causal) {
  int row = blockIdx.x;                 // (b*H+h)*S + s
  int s = row & (Sc - 1);
  float* p = sc + (long)row * Sc;
  int t0 = threadIdx.x, t1 = threadIdx.x + 256;
  int limit = causal ? (s + 1) : Sc;

  float v0 = (t0 < limit) ? p[t0] : NEG_INF;
  float v1 = (t1 < limit) ? p[t1] : NEG_INF;
  float mx = fmaxf(v0, v1);
  __shared__ float sm[4], sm2[4];
#pragma unroll
  for (int o = 32; o > 0; o >>= 1) mx = fmaxf(mx, __shfl_down(mx, o, 64));
  if ((threadIdx.x & 63) == 0) sm[threadIdx.x >> 6] = mx;
  __syncthreads();
  mx = fmaxf(fmaxf(sm[0], sm[1]), fmaxf(sm[2], sm[3]));

  float e0 = (t0 < limit) ? __expf(v0 - mx) : 0.f;
  float e1 = (t1 < limit) ? __expf(v1 - mx) : 0.f;
  float sum = e0 + e1;
#pragma unroll
  for (int o = 32; o > 0; o >>= 1) sum += __shfl_down(sum, o, 64);
  if ((threadIdx.x & 63) == 0) sm2[threadIdx.x >> 6] = sum;
  __syncthreads();
  sum = sm2[0] + sm2[1] + sm2[2] + sm2[3];
  float inv = 1.f / sum;
  p[t0] = e0 * inv;
  p[t1] = e1 * inv;
}

// ---------------- BatchNorm (training-mode, biased var over B*S) ----------
__global__ __launch_bounds__(256) void bn_stats(const float* __restrict__ x,
    const float* __restrict__ g, const float* __restrict__ b,
    float* __restrict__ scale, float* __restrict__ shift)
{
  int c = blockIdx.x;                 // channel
  float s = 0.f, s2 = 0.f;
  for (int r = threadIdx.x; r < Mc; r += 256) {
    float v = x[(long)r * Dc + c];
    s += v; s2 += v * v;
  }
  __shared__ float ssm[4], ssm2[4];
#pragma unroll
  for (int o = 32; o > 0; o >>= 1) { s += __shfl_down(s, o, 64); s2 += __shfl_down(s2, o, 64); }
  if ((threadIdx.x & 63) == 0) { ssm[threadIdx.x >> 6] = s; ssm2[threadIdx.x >> 6] = s2; }
  __syncthreads();
  if (threadIdx.x == 0) {
    s  = ssm[0] + ssm[1] + ssm[2] + ssm[3];
    s2 = ssm2[0] + ssm2[1] + ssm2[2] + ssm2[3];
    float mu  = s * (1.f / Mc);
    float var = s2 * (1.f / Mc) - mu * mu;
    float sc = g[c] * rsqrtf(var + BN_EPS);
    scale[c] = sc;
    shift[c] = b[c] - mu * sc;
  }
}

__global__ void bn_apply(float* __restrict__ x, const float* __restrict__ scale,
                         const float* __restrict__ shift) {
  int i = blockIdx.x * blockDim.x + threadIdx.x;
  if (i >= Mc * Dc) return;
  int c = i & 511;
  x[i] = x[i] * scale[c] + shift[c];
}

// ---------------- vocab softmax: 37000 cols, register-resident ------------
static constexpr int VT = 37;  // ceil(37000/1024)
__global__ __launch_bounds__(1024) void vocab_softmax(float* __restrict__ out) {
  long row = blockIdx.x;
  float* p = out + row * (long)Vc;
  float v[VT];
  float mx = NEG_INF;
#pragma unroll
  for (int j = 0; j < VT; j++) {
    int c = threadIdx.x + j * 1024;
    v[j] = (c < Vc) ? p[c] : NEG_INF;
    mx = fmaxf(mx, v[j]);
  }
  __shared__ float sm[16], sm2[16];
#pragma unroll
  for (int o = 32; o > 0; o >>= 1) mx = fmaxf(mx, __shfl_down(mx, o, 64));
  if ((threadIdx.x & 63) == 0) sm[threadIdx.x >> 6] = mx;
  __syncthreads();
  float m2 = sm[0];
#pragma unroll
  for (int i = 1; i < 16; i++) m2 = fmaxf(m2, sm[i]);
  mx = m2;

  float sum = 0.f;
#pragma unroll
  for (int j = 0; j < VT; j++) {
    int c = threadIdx.x + j * 1024;
    float e = (c < Vc) ? __expf(v[j] - mx) : 0.f;
    v[j] = e; sum += e;
  }
#pragma unroll
  for (int o = 32; o > 0; o >>= 1) sum += __shfl_down(sum, o, 64);
  if ((threadIdx.x & 63) == 0) sm2[threadIdx.x >> 6] = sum;
  __syncthreads();
  float s2 = 0.f;
#pragma unroll
  for (int i = 0; i < 16; i++) s2 += sm2[i];
  float inv = 1.f / s2;
#pragma unroll
  for (int j = 0; j < VT; j++) {
    int c = threadIdx.x + j * 1024;
    if (c < Vc) p[c] = v[j] * inv;
  }
}

// ---------------- orchestration ----------------
extern "C" void kernel_launch(void* const* d_in, const int* in_sizes, int n_in,
                              void* d_out, int out_size, void* d_ws, size_t ws_size,
                              hipStream_t stream) {
  const int*   idx   = (const int*)d_in[0];
  const float* enc   = (const float*)d_in[1];
  const float* emb   = (const float*)d_in[2];
  const float* Wq1   = (const float*)d_in[3];
  const float* Wk1   = (const float*)d_in[4];
  const float* Wv1   = (const float*)d_in[5];
  const float* Wo1   = (const float*)d_in[6];
  const float* Wq2   = (const float*)d_in[7];
  const float* Wk2   = (const float*)d_in[8];
  const float* Wv2   = (const float*)d_in[9];
  const float* Wo2   = (const float*)d_in[10];
  const float* gamma = (const float*)d_in[11];
  const float* beta  = (const float*)d_in[12];
  const float* W1    = (const float*)d_in[13];
  const float* b1    = (const float*)d_in[14];
  const float* W2    = (const float*)d_in[15];
  const float* b2    = (const float*)d_in[16];
  const float* Wout  = (const float*)d_in[17];
  const float* bout  = (const float*)d_in[18];
  float* out = (float*)d_out;

  // workspace layout (floats)
  float* ws = (float*)d_ws;
  const long MD = (long)Mc * Dc;                 // 1,048,576
  float* x      = ws;
  float* t0     = x  + MD;
  float* Q      = t0 + MD;                       // Q, Kb, Vb MUST stay contiguous (fused QKV)
  float* Kb     = Q  + MD;
  float* Vb     = Kb + MD;
  float* Ob     = Vb + MD;
  float* cc     = Ob + MD;
  float* ff1    = cc + MD;                       // 2048*2048
  float* scores = ff1 + (long)Mc * DFFc;         // 4*8*512*512
  float* scalep = scores + (long)Bc * Hc * Sc * Sc;
  float* shiftp = scalep + Dc;

  const int n1 = Mc * Dc;
  const int eb = (n1 + 255) / 256;
  const long sSD  = (long)Sc * Dc;   // x batch stride (per b)
  const long sDK  = (long)Dc * DKc;  // weight per-head stride
  const long sSK  = (long)Sc * DKc;  // Q/K/V per-(b,h) stride
  const long sSS  = (long)Sc * Sc;   // scores per-(b,h) stride

  embed_k<<<eb, 256, 0, stream>>>(idx, emb, x);

  for (int l = 0; l < NXc; l++) {
    // ======== self-attention (causal) ========
    {
      const float* wq = Wq1 + (long)l * Hc * Dc * DKc;
      const float* wk = Wk1 + (long)l * Hc * Dc * DKc;
      const float* wv = Wv1 + (long)l * Hc * Dc * DKc;
      const float* wo = Wo1 + (long)l * Dc * Dc;
      // fused QKV: 96 batches (t=Q/K/V x b x h)
      gemm_nn_mfma<<<dim3(Sc / 128, 1, 96), 256, 0, stream>>>(
          x, x, wq, wk, wv, nullptr, Q, Sc, DKc, Dc, sSD, sDK, sSK, 2, 1.f, 0);
      gemm_nt_mfma<<<dim3(4, 4, Bc * Hc), 256, 0, stream>>>(
          Q, Kb, scores, sSK, sSK, sSS, 0.125f, 1);
      attn_softmax<<<Bc * Hc * Sc, 256, 0, stream>>>(scores, 1);
      gemm_nn_mfma<<<dim3(Sc / 128, 1, Bc * Hc), 256, 0, stream>>>(
          scores, nullptr, Vb, nullptr, nullptr, nullptr, Ob, Sc, DKc, Sc, sSS, sSK, sSK, 0, 1.f, 0);
      concat_k<<<eb, 256, 0, stream>>>(Ob, cc);
      gemm_nn_mfma<<<dim3(Mc / 128, Dc / 128, 1), 256, 0, stream>>>(
          cc, nullptr, wo, nullptr, nullptr, nullptr, t0, Mc, Dc, Dc, 0, 0, 0, 0, 1.f, 0);
      add_k<<<eb, 256, 0, stream>>>(x, t0, n1);
      bn_stats<<<Dc, 256, 0, stream>>>(x, gamma + (long)(l * 3 + 0) * Dc, beta + (long)(l * 3 + 0) * Dc, scalep, shiftp);
      bn_apply<<<eb, 256, 0, stream>>>(x, scalep, shiftp);
    }
    // ======== cross-attention ========
    {
      const float* wq = Wq2 + (long)l * Hc * Dc * DKc;
      const float* wk = Wk2 + (long)l * Hc * Dc * DKc;
      const float* wv = Wv2 + (long)l * Hc * Dc * DKc;
      const float* wo = Wo2 + (long)l * Dc * Dc;
      gemm_nn_mfma<<<dim3(Sc / 128, 1, 96), 256, 0, stream>>>(
          x, enc, wq, wk, wv, nullptr, Q, Sc, DKc, Dc, sSD, sDK, sSK, 2, 1.f, 0);
      gemm_nt_mfma<<<dim3(4, 4, Bc * Hc), 256, 0, stream>>>(
          Q, Kb, scores, sSK, sSK, sSS, 0.125f, 0);
      attn_softmax<<<Bc * Hc * Sc, 256, 0, stream>>>(scores, 0);
      gemm_nn_mfma<<<dim3(Sc / 128, 1, Bc * Hc), 256, 0, stream>>>(
          scores, nullptr, Vb, nullptr, nullptr, nullptr, Ob, Sc, DKc, Sc, sSS, sSK, sSK, 0, 1.f, 0);
      concat_k<<<eb, 256, 0, stream>>>(Ob, cc);
      gemm_nn_mfma<<<dim3(Mc / 128, Dc / 128, 1), 256, 0, stream>>>(
          cc, nullptr, wo, nullptr, nullptr, nullptr, t0, Mc, Dc, Dc, 0, 0, 0, 0, 1.f, 0);
      add_k<<<eb, 256, 0, stream>>>(x, t0, n1);
      bn_stats<<<Dc, 256, 0, stream>>>(x, gamma + (long)(l * 3 + 1) * Dc, beta + (long)(l * 3 + 1) * Dc, scalep, shiftp);
      bn_apply<<<eb, 256, 0, stream>>>(x, scalep, shiftp);
    }
    // ======== FFN ========
    {
      gemm_nn_mfma<<<dim3(Mc / 128, DFFc / 128, 1), 256, 0, stream>>>(
          x, nullptr, W1 + (long)l * Dc * DFFc, nullptr, nullptr, b1 + (long)l * DFFc, ff1,
          Mc, DFFc, Dc, 0, 0, 0, 0, 1.f, 1);
      gemm_nn_mfma<<<dim3(Mc / 128, Dc / 128, 1), 256, 0, stream>>>(
          ff1, nullptr, W2 + (long)l * DFFc * Dc, nullptr, nullptr, b2 + (long)l * Dc, t0,
          Mc, Dc, DFFc, 0, 0, 0, 0, 1.f, 0);
      add_k<<<eb, 256, 0, stream>>>(x, t0, n1);
      bn_stats<<<Dc, 256, 0, stream>>>(x, gamma + (long)(l * 3 + 2) * Dc, beta + (long)(l * 3 + 2) * Dc, scalep, shiftp);
      bn_apply<<<eb, 256, 0, stream>>>(x, scalep, shiftp);
    }
  }

  // ======== final projection + vocab softmax ========
  gemm_nn_mfma<<<dim3(Mc / 128, (Vc + 127) / 128, 1), 256, 0, stream>>>(
      x, nullptr, Wout, nullptr, nullptr, bout, out, Mc, Vc, Dc, 0, 0, 0, 0, 1.f, 0);
  vocab_softmax<<<Mc, 1024, 0, stream>>>(out);
}

// Round 2
// 2419.850 us; speedup vs baseline: 2.5123x; 1.4531x over previous
//
#include <hip/hip_runtime.h>
#include <math.h>

// ---- problem constants ----
static constexpr int Bc   = 4;
static constexpr int Sc   = 512;
static constexpr int Dc   = 512;     // d_model
static constexpr int Hc   = 8;
static constexpr int DKc  = 64;
static constexpr int NXc  = 6;
static constexpr int DFFc = 2048;
static constexpr int Vc   = 37000;
static constexpr int Mc   = Bc * Sc; // 2048 rows
static constexpr float BN_EPS = 1e-5f;

#define NEG_INF (-1e30f)

// ---- MFMA types / helpers ----
using bf16x8 = __attribute__((ext_vector_type(8))) short;
using f32x4  = __attribute__((ext_vector_type(4))) float;

__device__ inline unsigned short f2bf(float f) {
  union { float f; unsigned u; } v; v.f = f;
  unsigned r = v.u + 0x7FFFu + ((v.u >> 16) & 1u);   // RNE
  return (unsigned short)(r >> 16);
}

__device__ inline bf16x8 cvt8(float4 a, float4 b) {
  union { bf16x8 v; unsigned short s[8]; } u;
  u.s[0] = f2bf(a.x); u.s[1] = f2bf(a.y); u.s[2] = f2bf(a.z); u.s[3] = f2bf(a.w);
  u.s[4] = f2bf(b.x); u.s[5] = f2bf(b.y); u.s[6] = f2bf(b.z); u.s[7] = f2bf(b.w);
  return u.v;
}

__device__ inline bf16x8 pack8(const float* f) {
  union { bf16x8 v; unsigned short s[8]; } u;
#pragma unroll
  for (int i = 0; i < 8; i++) u.s[i] = f2bf(f[i]);
  return u.v;
}

// ---------------- elementwise ----------------
__global__ void embed_k(const int* __restrict__ idx, const float* __restrict__ emb,
                        float* __restrict__ x) {
  int i = blockIdx.x * blockDim.x + threadIdx.x;
  if (i >= Mc * Dc) return;
  int r = i >> 9;          // / 512
  int d = i & 511;
  x[i] = emb[(long)idx[r] * Dc + d] * 8.0f;   // * sqrt(d_k)=8
}

// ============ big GEMM: 128x128 tile, BK=32, fragment-order LDS ============
// LDS layout: unit u = mi*64 + kg*16 + fr holds A[row=mi*16+fr][k=kg*8..kg*8+7]
// -> fragment read addr = (mi_base+i)*1024 + lane*16 : conflict-free contiguous.
// mode==0: plain (A+z*aB, B0+z*bB). bias/relu optional. fp32 in/out.
__global__ __launch_bounds__(256) void gemm_nn_mfma(
    const float* __restrict__ A, const float* __restrict__ B0,
    const float* __restrict__ bias, float* __restrict__ C,
    int M, int N, int K, long aB, long bB, long cB,
    float alpha, int relu)
{
  int z = blockIdx.z;
  const float* Ap = A  + (long)z * aB;
  const float* Bp = B0 + (long)z * bB;
  C += (long)z * cB;

  __shared__ unsigned short sA[128 * 32];  // 8 KB, fragment-order
  __shared__ unsigned short sB[128 * 32];

  int tid  = threadIdx.x;
  int lane = tid & 63;
  int wave = tid >> 6;
  int row0 = blockIdx.x * 128, col0 = blockIdx.y * 128;

  // A staging: thread -> row r=tid>>1 (0..127), k-half kh=(tid&1)*16
  int ar = tid >> 1, akh = (tid & 1) * 16;
  // B staging: thread -> col c=tid&127, k-half bkh=(tid>>7)*16; scalar coalesced loads
  int bcc = tid & 127, bkh = (tid >> 7) * 16;
  bool bok = (col0 + bcc < N);

  float4 ra[4];
  float  rbs[16];

  auto load_tiles = [&](int k0) {
#pragma unroll
    for (int p = 0; p < 4; p++)
      ra[p] = *(const float4*)(Ap + (long)(row0 + ar) * K + k0 + akh + p * 4);
#pragma unroll
    for (int i = 0; i < 16; i++)
      rbs[i] = bok ? Bp[(long)(k0 + bkh + i) * N + col0 + bcc] : 0.f;
  };

  f32x4 zero4 = {0.f, 0.f, 0.f, 0.f};
  f32x4 acc[4][4];
#pragma unroll
  for (int i = 0; i < 4; i++)
#pragma unroll
    for (int j = 0; j < 4; j++) acc[i][j] = zero4;

  int m0 = (wave >> 1) * 64, n0 = (wave & 1) * 64;
  int fr = lane & 15;

  // precomputed staging unit indices
  int aU0 = (ar >> 4) * 64 + ((akh >> 3) + 0) * 16 + (ar & 15);
  int aU1 = (ar >> 4) * 64 + ((akh >> 3) + 1) * 16 + (ar & 15);
  int bU0 = (bcc >> 4) * 64 + ((bkh >> 3) + 0) * 16 + (bcc & 15);
  int bU1 = (bcc >> 4) * 64 + ((bkh >> 3) + 1) * 16 + (bcc & 15);

  load_tiles(0);
  for (int k0 = 0; ; ) {
    __syncthreads();   // previous iteration's LDS readers done
    *(bf16x8*)&sA[aU0 * 8] = cvt8(ra[0], ra[1]);
    *(bf16x8*)&sA[aU1 * 8] = cvt8(ra[2], ra[3]);
    *(bf16x8*)&sB[bU0 * 8] = pack8(&rbs[0]);
    *(bf16x8*)&sB[bU1 * 8] = pack8(&rbs[8]);
    __syncthreads();

    int kn = k0 + 32;
    bool more = kn < K;
    if (more) load_tiles(kn);   // prefetch next tile under the MFMA phase

    bf16x8 af[4], bfr[4];
#pragma unroll
    for (int i = 0; i < 4; i++) {
      af[i]  = *(const bf16x8*)&sA[(((m0 >> 4) + i) * 64 + lane) * 8];
      bfr[i] = *(const bf16x8*)&sB[(((n0 >> 4) + i) * 64 + lane) * 8];
    }
#pragma unroll
    for (int mi = 0; mi < 4; mi++)
#pragma unroll
      for (int ni = 0; ni < 4; ni++)
        acc[mi][ni] = __builtin_amdgcn_mfma_f32_16x16x32_bf16(af[mi], bfr[ni], acc[mi][ni], 0, 0, 0);

    if (!more) break;
    k0 = kn;
  }

  // epilogue: C/D layout col=lane&15, row=(lane>>4)*4+j
  int rg = (lane >> 4) << 2;
#pragma unroll
  for (int ni = 0; ni < 4; ni++) {
    int col = col0 + n0 + ni * 16 + fr;
    if (col < N) {
      float bv = bias ? bias[col] : 0.f;
#pragma unroll
      for (int mi = 0; mi < 4; mi++) {
        int r0 = row0 + m0 + mi * 16 + rg;
#pragma unroll
        for (int j = 0; j < 4; j++) {
          float o = acc[mi][ni][j] * alpha + bv;
          if (relu) o = fmaxf(o, 0.f);
          C[(long)(r0 + j) * N + col] = o;
        }
      }
    }
  }
}

// ============ small GEMM: 64x64 tile, BK=64, fragment-order LDS ============
// For grid-starved GEMMs (QKV / PV / Wo / FFN2). M,N,K multiples of 64.
// mode==0: plain.  mode==2: fused QKV (z=t*32+zz; A-src t==0?A:A2, B {B0,B1,B2}[t]).
// mode==3: PV with fused concat: C += (z/H)*S*D + (z%H)*64, ldc=Dc.
__global__ __launch_bounds__(256) void gemm64(
    const float* __restrict__ A, const float* __restrict__ A2,
    const float* __restrict__ B0, const float* __restrict__ B1, const float* __restrict__ B2,
    const float* __restrict__ bias, float* __restrict__ C,
    int N, int K, long aB, long bB, long cB, int mode, int relu)
{
  int z = blockIdx.z;
  const float* Ap;
  const float* Bp;
  float* Cp;
  int ldc;
  if (mode == 2) {
    int t = z >> 5, zz = z & 31;
    Ap = (t == 0 ? A : A2) + (long)(zz >> 3) * aB;
    Bp = (t == 0 ? B0 : (t == 1 ? B1 : B2)) + (long)(zz & 7) * bB;
    Cp = C + (long)z * cB; ldc = N;
  } else if (mode == 3) {
    Ap = A + (long)z * aB; Bp = B0 + (long)z * bB;
    Cp = C + (long)(z >> 3) * ((long)Sc * Dc) + (long)(z & 7) * 64; ldc = Dc;
  } else {
    Ap = A + (long)z * aB; Bp = B0 + (long)z * bB;
    Cp = C + (long)z * cB; ldc = N;
  }

  __shared__ unsigned short sA[64 * 64];  // 8 KB
  __shared__ unsigned short sB[64 * 64];

  int tid = threadIdx.x, lane = tid & 63, wave = tid >> 6;
  int row0 = blockIdx.x * 64, col0 = blockIdx.y * 64;

  // A staging: r = tid>>2 (0..63), kq = (tid&3)*16
  int ar = tid >> 2, akq = (tid & 3) * 16;
  // B staging: c = lane, kq = wave*16 ; coalesced scalar loads
  int bcc = lane, bkq = wave * 16;

  float4 ra[4];
  float  rbs[16];
  auto load_tiles = [&](int k0) {
#pragma unroll
    for (int p = 0; p < 4; p++)
      ra[p] = *(const float4*)(Ap + (long)(row0 + ar) * K + k0 + akq + p * 4);
#pragma unroll
    for (int i = 0; i < 16; i++)
      rbs[i] = Bp[(long)(k0 + bkq + i) * N + col0 + bcc];
  };

  // unit idx(r,k) = ((r>>4)*2 + (k>>5))*64 + ((k>>3)&3)*16 + (r&15)
  int aU0 = ((ar >> 4) * 2 + (akq >> 5)) * 64 + ((akq >> 3) & 3) * 16 + (ar & 15);
  int aU1 = ((ar >> 4) * 2 + ((akq + 8) >> 5)) * 64 + (((akq + 8) >> 3) & 3) * 16 + (ar & 15);
  int bU0 = ((bcc >> 4) * 2 + (bkq >> 5)) * 64 + ((bkq >> 3) & 3) * 16 + (bcc & 15);
  int bU1 = ((bcc >> 4) * 2 + ((bkq + 8) >> 5)) * 64 + (((bkq + 8) >> 3) & 3) * 16 + (bcc & 15);

  f32x4 zero4 = {0.f, 0.f, 0.f, 0.f};
  f32x4 acc[2][2];
  acc[0][0] = zero4; acc[0][1] = zero4; acc[1][0] = zero4; acc[1][1] = zero4;

  int m0 = (wave >> 1) * 32, n0 = (wave & 1) * 32;
  int fr = lane & 15;

  load_tiles(0);
  for (int k0 = 0; ; ) {
    __syncthreads();
    *(bf16x8*)&sA[aU0 * 8] = cvt8(ra[0], ra[1]);
    *(bf16x8*)&sA[aU1 * 8] = cvt8(ra[2], ra[3]);
    *(bf16x8*)&sB[bU0 * 8] = pack8(&rbs[0]);
    *(bf16x8*)&sB[bU1 * 8] = pack8(&rbs[8]);
    __syncthreads();

    int kn = k0 + 64;
    bool more = kn < K;
    if (more) load_tiles(kn);

    bf16x8 af[2][2], bf[2][2];
#pragma unroll
    for (int i = 0; i < 2; i++)
#pragma unroll
      for (int kk = 0; kk < 2; kk++) {
        af[i][kk] = *(const bf16x8*)&sA[((((m0 >> 4) + i) * 2 + kk) * 64 + lane) * 8];
        bf[i][kk] = *(const bf16x8*)&sB[((((n0 >> 4) + i) * 2 + kk) * 64 + lane) * 8];
      }
#pragma unroll
    for (int kk = 0; kk < 2; kk++)
#pragma unroll
      for (int mi = 0; mi < 2; mi++)
#pragma unroll
        for (int ni = 0; ni < 2; ni++)
          acc[mi][ni] = __builtin_amdgcn_mfma_f32_16x16x32_bf16(af[mi][kk], bf[ni][kk], acc[mi][ni], 0, 0, 0);

    if (!more) break;
    k0 = kn;
  }

  int rg = (lane >> 4) << 2;
#pragma unroll
  for (int ni = 0; ni < 2; ni++) {
    int col = col0 + n0 + ni * 16 + fr;
    float bv = bias ? bias[col] : 0.f;
#pragma unroll
    for (int mi = 0; mi < 2; mi++) {
      int r0 = row0 + m0 + mi * 16 + rg;
#pragma unroll
      for (int j = 0; j < 4; j++) {
        float o = acc[mi][ni][j] + bv;
        if (relu) o = fmaxf(o, 0.f);
        Cp[(long)(r0 + j) * ldc + col] = o;
      }
    }
  }
}

// ---------------- bf16-MFMA GEMM NT: scores = alpha * Q @ K^T ----------------
__global__ __launch_bounds__(256) void gemm_nt_mfma(
    const float* __restrict__ A, const float* __restrict__ Bm, float* __restrict__ C,
    long aB, long bB, long cB, float alpha, int causal)
{
  if (causal && blockIdx.y > blockIdx.x) return;   // tile entirely above diagonal
  int z = blockIdx.z;
  const float* Ap = A  + (long)z * aB;
  const float* Bp = Bm + (long)z * bB;
  float* Cp = C + (long)z * cB;

  int tid = threadIdx.x, lane = tid & 63, wave = tid >> 6;
  int m0 = blockIdx.x * 128 + (wave >> 1) * 64;
  int n0 = blockIdx.y * 128 + (wave & 1) * 64;
  int fr = lane & 15, fk = (lane >> 4) * 8;

  bf16x8 af[4][2];
#pragma unroll
  for (int mi = 0; mi < 4; mi++) {
    const float* p = Ap + (long)(m0 + mi * 16 + fr) * DKc + fk;
    af[mi][0] = cvt8(*(const float4*)p,        *(const float4*)(p + 4));
    af[mi][1] = cvt8(*(const float4*)(p + 32), *(const float4*)(p + 36));
  }

  f32x4 zero4 = {0.f, 0.f, 0.f, 0.f};
  f32x4 acc[4][4];
#pragma unroll
  for (int i = 0; i < 4; i++)
#pragma unroll
    for (int j = 0; j < 4; j++) acc[i][j] = zero4;

#pragma unroll
  for (int ni = 0; ni < 4; ni++) {
    const float* q = Bp + (long)(n0 + ni * 16 + fr) * DKc + fk;
    bf16x8 b0 = cvt8(*(const float4*)q,        *(const float4*)(q + 4));
    bf16x8 b1 = cvt8(*(const float4*)(q + 32), *(const float4*)(q + 36));
#pragma unroll
    for (int mi = 0; mi < 4; mi++) {
      acc[mi][ni] = __builtin_amdgcn_mfma_f32_16x16x32_bf16(af[mi][0], b0, acc[mi][ni], 0, 0, 0);
      acc[mi][ni] = __builtin_amdgcn_mfma_f32_16x16x32_bf16(af[mi][1], b1, acc[mi][ni], 0, 0, 0);
    }
  }

  int rg = (lane >> 4) << 2;
#pragma unroll
  for (int ni = 0; ni < 4; ni++) {
    int col = n0 + ni * 16 + fr;
#pragma unroll
    for (int mi = 0; mi < 4; mi++) {
      int r0 = m0 + mi * 16 + rg;
#pragma unroll
      for (int j = 0; j < 4; j++)
        Cp[(long)(r0 + j) * Sc + col] = acc[mi][ni][j] * alpha;
    }
  }
}

// ---------------- attention softmax (row of 512, causal mask optional) ----
__global__ __launch_bounds__(256) void attn_softmax(float* __restrict__ sc, int causal) {
  int row = blockIdx.x;                 // (b*H+h)*S + s
  int s = row & (Sc - 1);
  float* p = sc + (long)row * Sc;
  int t0 = threadIdx.x, t1 = threadIdx.x + 256;
  int limit = causal ? (s + 1) : Sc;

  float v0 = (t0 < limit) ? p[t0] : NEG_INF;
  float v1 = (t1 < limit) ? p[t1] : NEG_INF;
  float mx = fmaxf(v0, v1);
  __shared__ float sm[4], sm2[4];
#pragma unroll
  for (int o = 32; o > 0; o >>= 1) mx = fmaxf(mx, __shfl_down(mx, o, 64));
  if ((threadIdx.x & 63) == 0) sm[threadIdx.x >> 6] = mx;
  __syncthreads();
  mx = fmaxf(fmaxf(sm[0], sm[1]), fmaxf(sm[2], sm[3]));

  float e0 = (t0 < limit) ? __expf(v0 - mx) : 0.f;
  float e1 = (t1 < limit) ? __expf(v1 - mx) : 0.f;
  float sum = e0 + e1;
#pragma unroll
  for (int o = 32; o > 0; o >>= 1) sum += __shfl_down(sum, o, 64);
  if ((threadIdx.x & 63) == 0) sm2[threadIdx.x >> 6] = sum;
  __syncthreads();
  sum = sm2[0] + sm2[1] + sm2[2] + sm2[3];
  float inv = 1.f / sum;
  p[t0] = e0 * inv;
  p[t1] = e1 * inv;
}

// -------- fused residual add + BN partial stats (deterministic) --------
// grid 128 blocks x 256 threads; block handles 16 rows; thread owns 2 channels.
// part layout: partS[c][128], partQ[c][128] (contiguous per channel for finalize).
__global__ __launch_bounds__(256) void add_stats(
    float* __restrict__ x, const float* __restrict__ y, float* __restrict__ part)
{
  int blk = blockIdx.x;
  int c = threadIdx.x * 2;
  int r0 = blk * 16;
  float s0 = 0.f, s1 = 0.f, q0 = 0.f, q1 = 0.f;
#pragma unroll 4
  for (int r = r0; r < r0 + 16; r++) {
    long off = (long)r * Dc + c;
    float2 v = *(const float2*)&x[off];
    float2 w = *(const float2*)&y[off];
    v.x += w.x; v.y += w.y;
    *(float2*)&x[off] = v;
    s0 += v.x; q0 += v.x * v.x;
    s1 += v.y; q1 += v.y * v.y;
  }
  part[(long)c * 128 + blk] = s0;
  part[(long)(c + 1) * 128 + blk] = s1;
  part[Dc * 128 + (long)c * 128 + blk] = q0;
  part[Dc * 128 + (long)(c + 1) * 128 + blk] = q1;
}

__global__ __launch_bounds__(256) void bn_finalize(
    const float* __restrict__ part, const float* __restrict__ g,
    const float* __restrict__ b, float* __restrict__ scale, float* __restrict__ shift)
{
  int c = blockIdx.x * 256 + threadIdx.x;
  if (c >= Dc) return;
  const float* ps = part + (long)c * 128;
  const float* pq = part + Dc * 128 + (long)c * 128;
  float s = 0.f, q = 0.f;
#pragma unroll 8
  for (int i = 0; i < 128; i++) { s += ps[i]; q += pq[i]; }
  float mu  = s * (1.f / Mc);
  float var = q * (1.f / Mc) - mu * mu;
  float sc = g[c] * rsqrtf(var + BN_EPS);
  scale[c] = sc;
  shift[c] = b[c] - mu * sc;
}

__global__ void bn_apply(float* __restrict__ x, const float* __restrict__ scale,
                         const float* __restrict__ shift) {
  int i = blockIdx.x * blockDim.x + threadIdx.x;
  if (i >= Mc * Dc) return;
  int c = i & 511;
  x[i] = x[i] * scale[c] + shift[c];
}

// ---------------- vocab softmax: 37000 cols, register-resident ------------
static constexpr int VT = 37;  // ceil(37000/1024)
__global__ __launch_bounds__(1024) void vocab_softmax(float* __restrict__ out) {
  long row = blockIdx.x;
  float* p = out + row * (long)Vc;
  float v[VT];
  float mx = NEG_INF;
#pragma unroll
  for (int j = 0; j < VT; j++) {
    int c = threadIdx.x + j * 1024;
    v[j] = (c < Vc) ? p[c] : NEG_INF;
    mx = fmaxf(mx, v[j]);
  }
  __shared__ float sm[16], sm2[16];
#pragma unroll
  for (int o = 32; o > 0; o >>= 1) mx = fmaxf(mx, __shfl_down(mx, o, 64));
  if ((threadIdx.x & 63) == 0) sm[threadIdx.x >> 6] = mx;
  __syncthreads();
  float m2 = sm[0];
#pragma unroll
  for (int i = 1; i < 16; i++) m2 = fmaxf(m2, sm[i]);
  mx = m2;

  float sum = 0.f;
#pragma unroll
  for (int j = 0; j < VT; j++) {
    int c = threadIdx.x + j * 1024;
    float e = (c < Vc) ? __expf(v[j] - mx) : 0.f;
    v[j] = e; sum += e;
  }
#pragma unroll
  for (int o = 32; o > 0; o >>= 1) sum += __shfl_down(sum, o, 64);
  if ((threadIdx.x & 63) == 0) sm2[threadIdx.x >> 6] = sum;
  __syncthreads();
  float s2 = 0.f;
#pragma unroll
  for (int i = 0; i < 16; i++) s2 += sm2[i];
  float inv = 1.f / s2;
#pragma unroll
  for (int j = 0; j < VT; j++) {
    int c = threadIdx.x + j * 1024;
    if (c < Vc) p[c] = v[j] * inv;
  }
}

// ---------------- orchestration ----------------
extern "C" void kernel_launch(void* const* d_in, const int* in_sizes, int n_in,
                              void* d_out, int out_size, void* d_ws, size_t ws_size,
                              hipStream_t stream) {
  const int*   idx   = (const int*)d_in[0];
  const float* enc   = (const float*)d_in[1];
  const float* emb   = (const float*)d_in[2];
  const float* Wq1   = (const float*)d_in[3];
  const float* Wk1   = (const float*)d_in[4];
  const float* Wv1   = (const float*)d_in[5];
  const float* Wo1   = (const float*)d_in[6];
  const float* Wq2   = (const float*)d_in[7];
  const float* Wk2   = (const float*)d_in[8];
  const float* Wv2   = (const float*)d_in[9];
  const float* Wo2   = (const float*)d_in[10];
  const float* gamma = (const float*)d_in[11];
  const float* beta  = (const float*)d_in[12];
  const float* W1    = (const float*)d_in[13];
  const float* b1    = (const float*)d_in[14];
  const float* W2    = (const float*)d_in[15];
  const float* b2    = (const float*)d_in[16];
  const float* Wout  = (const float*)d_in[17];
  const float* bout  = (const float*)d_in[18];
  float* out = (float*)d_out;

  // workspace layout (floats)
  float* ws = (float*)d_ws;
  const long MD = (long)Mc * Dc;                 // 1,048,576
  float* x      = ws;
  float* t0     = x  + MD;
  float* Q      = t0 + MD;                       // Q, Kb, Vb MUST stay contiguous (fused QKV)
  float* Kb     = Q  + MD;
  float* Vb     = Kb + MD;
  float* cc     = Vb + MD;
  float* ff1    = cc + MD;                       // 2048*2048
  float* scores = ff1 + (long)Mc * DFFc;         // 4*8*512*512
  float* scalep = scores + (long)Bc * Hc * Sc * Sc;
  float* shiftp = scalep + Dc;
  float* part   = shiftp + Dc;                   // 2*512*128 floats

  const int n1 = Mc * Dc;
  const int eb = (n1 + 255) / 256;
  const long sSD  = (long)Sc * Dc;   // x batch stride (per b)
  const long sDK  = (long)Dc * DKc;  // weight per-head stride
  const long sSK  = (long)Sc * DKc;  // Q/K/V per-(b,h) stride
  const long sSS  = (long)Sc * Sc;   // scores per-(b,h) stride

  embed_k<<<eb, 256, 0, stream>>>(idx, emb, x);

  for (int l = 0; l < NXc; l++) {
    // ======== self-attention (causal) ========
    {
      const float* wq = Wq1 + (long)l * Hc * Dc * DKc;
      const float* wk = Wk1 + (long)l * Hc * Dc * DKc;
      const float* wv = Wv1 + (long)l * Hc * Dc * DKc;
      const float* wo = Wo1 + (long)l * Dc * Dc;
      // fused QKV: 96 batches (t=Q/K/V x b x h), 64x64 tiles -> 768 blocks
      gemm64<<<dim3(Sc / 64, 1, 96), 256, 0, stream>>>(
          x, x, wq, wk, wv, nullptr, Q, DKc, Dc, sSD, sDK, sSK, 2, 0);
      gemm_nt_mfma<<<dim3(4, 4, Bc * Hc), 256, 0, stream>>>(
          Q, Kb, scores, sSK, sSK, sSS, 0.125f, 1);
      attn_softmax<<<Bc * Hc * Sc, 256, 0, stream>>>(scores, 1);
      // PV with fused concat -> cc
      gemm64<<<dim3(Sc / 64, 1, Bc * Hc), 256, 0, stream>>>(
          scores, nullptr, Vb, nullptr, nullptr, nullptr, cc, DKc, Sc, sSS, sSK, 0, 3, 0);
      // Wo: 64x64 tiles -> 256 blocks
      gemm64<<<dim3(Mc / 64, Dc / 64, 1), 256, 0, stream>>>(
          cc, nullptr, wo, nullptr, nullptr, nullptr, t0, Dc, Dc, 0, 0, 0, 0, 0);
      add_stats<<<128, 256, 0, stream>>>(x, t0, part);
      bn_finalize<<<2, 256, 0, stream>>>(part, gamma + (long)(l * 3 + 0) * Dc, beta + (long)(l * 3 + 0) * Dc, scalep, shiftp);
      bn_apply<<<eb, 256, 0, stream>>>(x, scalep, shiftp);
    }
    // ======== cross-attention ========
    {
      const float* wq = Wq2 + (long)l * Hc * Dc * DKc;
      const float* wk = Wk2 + (long)l * Hc * Dc * DKc;
      const float* wv = Wv2 + (long)l * Hc * Dc * DKc;
      const float* wo = Wo2 + (long)l * Dc * Dc;
      gemm64<<<dim3(Sc / 64, 1, 96), 256, 0, stream>>>(
          x, enc, wq, wk, wv, nullptr, Q, DKc, Dc, sSD, sDK, sSK, 2, 0);
      gemm_nt_mfma<<<dim3(4, 4, Bc * Hc), 256, 0, stream>>>(
          Q, Kb, scores, sSK, sSK, sSS, 0.125f, 0);
      attn_softmax<<<Bc * Hc * Sc, 256, 0, stream>>>(scores, 0);
      gemm64<<<dim3(Sc / 64, 1, Bc * Hc), 256, 0, stream>>>(
          scores, nullptr, Vb, nullptr, nullptr, nullptr, cc, DKc, Sc, sSS, sSK, 0, 3, 0);
      gemm64<<<dim3(Mc / 64, Dc / 64, 1), 256, 0, stream>>>(
          cc, nullptr, wo, nullptr, nullptr, nullptr, t0, Dc, Dc, 0, 0, 0, 0, 0);
      add_stats<<<128, 256, 0, stream>>>(x, t0, part);
      bn_finalize<<<2, 256, 0, stream>>>(part, gamma + (long)(l * 3 + 1) * Dc, beta + (long)(l * 3 + 1) * Dc, scalep, shiftp);
      bn_apply<<<eb, 256, 0, stream>>>(x, scalep, shiftp);
    }
    // ======== FFN ========
    {
      gemm_nn_mfma<<<dim3(Mc / 128, DFFc / 128, 1), 256, 0, stream>>>(
          x, W1 + (long)l * Dc * DFFc, b1 + (long)l * DFFc, ff1,
          Mc, DFFc, Dc, 0, 0, 0, 1.f, 1);
      gemm64<<<dim3(Mc / 64, Dc / 64, 1), 256, 0, stream>>>(
          ff1, nullptr, W2 + (long)l * DFFc * Dc, nullptr, nullptr, b2 + (long)l * Dc, t0,
          Dc, DFFc, 0, 0, 0, 0, 0);
      add_stats<<<128, 256, 0, stream>>>(x, t0, part);
      bn_finalize<<<2, 256, 0, stream>>>(part, gamma + (long)(l * 3 + 2) * Dc, beta + (long)(l * 3 + 2) * Dc, scalep, shiftp);
      bn_apply<<<eb, 256, 0, stream>>>(x, scalep, shiftp);
    }
  }

  // ======== final projection + vocab softmax ========
  gemm_nn_mfma<<<dim3(Mc / 128, (Vc + 127) / 128, 1), 256, 0, stream>>>(
      x, Wout, bout, out, Mc, Vc, Dc, 0, 0, 0, 1.f, 0);
  vocab_softmax<<<Mc, 1024, 0, stream>>>(out);
}

// Round 3
// 2325.214 us; speedup vs baseline: 2.6145x; 1.0407x over previous
//
#include <hip/hip_runtime.h>
#include <math.h>

// ---- problem constants ----
static constexpr int Bc   = 4;
static constexpr int Sc   = 512;
static constexpr int Dc   = 512;     // d_model
static constexpr int Hc   = 8;
static constexpr int DKc  = 64;
static constexpr int NXc  = 6;
static constexpr int DFFc = 2048;
static constexpr int Vc   = 37000;
static constexpr int Mc   = Bc * Sc; // 2048 rows
static constexpr float BN_EPS = 1e-5f;

#define NEG_INF (-1e30f)

typedef unsigned short u16;
using bf16x8 = __attribute__((ext_vector_type(8))) short;
using us8    = __attribute__((ext_vector_type(8))) unsigned short;
using f32x4  = __attribute__((ext_vector_type(4))) float;

__device__ inline u16 f2bf(float f) {
  union { float f; unsigned u; } v; v.f = f;
  unsigned r = v.u + 0x7FFFu + ((v.u >> 16) & 1u);   // RNE
  return (u16)(r >> 16);
}

// async global->LDS, 16B per lane; LDS dest = wave-uniform base + lane*16
__device__ inline void gload16(const void* g, void* l) {
  __builtin_amdgcn_global_load_lds(
      (const __attribute__((address_space(1))) unsigned int*)g,
      (__attribute__((address_space(3))) unsigned int*)l, 16, 0, 0);
}

// ---------------- elementwise ----------------
__global__ void embed_k(const int* __restrict__ idx, const float* __restrict__ emb,
                        float* __restrict__ x, u16* __restrict__ xh) {
  int i = blockIdx.x * blockDim.x + threadIdx.x;
  if (i >= Mc * Dc) return;
  int r = i >> 9, d = i & 511;
  float v = emb[(long)idx[r] * Dc + d] * 8.0f;   // * sqrt(d_k)=8
  x[i] = v;
  xh[i] = f2bf(v);
}

__global__ void cvt_bf16(const float* __restrict__ in, u16* __restrict__ out, int n4) {
  int i = blockIdx.x * blockDim.x + threadIdx.x;
  if (i >= n4) return;
  float4 v = ((const float4*)in)[i];
  unsigned a = (unsigned)f2bf(v.x) | ((unsigned)f2bf(v.y) << 16);
  unsigned b = (unsigned)f2bf(v.z) | ((unsigned)f2bf(v.w) << 16);
  uint2 w; w.x = a; w.y = b;
  ((uint2*)out)[i] = w;
}

// ---------------- weight transpose+convert: in [R][C] f32 -> out [Cpad][R] bf16 ----
__device__ void wtile(const float* src, int ldin, int cval, u16* dst, int ldout) {
  __shared__ u16 ls[64][65];
  int tx = threadIdx.x & 63, ty = threadIdx.x >> 6;
#pragma unroll
  for (int p = 0; p < 16; p++) {
    int r = p * 4 + ty;
    float v = (tx < cval) ? src[(long)r * ldin + tx] : 0.f;
    ls[tx][r] = f2bf(v);
  }
  __syncthreads();
#pragma unroll
  for (int p = 0; p < 16; p++) {
    int oc = p * 4 + ty;
    dst[(long)oc * ldout + tx] = ls[oc][tx];
  }
}

// Wb layout (uniform stride HT = nl*262144 elems):
// k*HT: q1=0,k1=1,v1=2,q2=3,k2=4,v2=5,o1=6,o2=7, w1=8(.. 4 HT), w2=12(.. 4 HT), wout=16
__global__ __launch_bounds__(256) void wconv(
    const float* q1, const float* k1, const float* v1, const float* o1,
    const float* q2, const float* k2, const float* v2, const float* o2,
    const float* w1, const float* w2, const float* wout,
    u16* Wb, u16* WoutT, int nl, int l0)
{
  long HT = (long)nl * 262144;
  int u = blockIdx.x;
  int layerBlocks = nl * 1024;
  if (u < layerBlocks) {
    int lslot = u >> 10;                 // u / 1024
    int l = l0 + lslot;
    int t = u & 1023;
    if (t < 384) {          // head tensors [512][64] -> [64][512]
      int ten = t >> 6, w = t & 63, h = w >> 3, rt = w & 7;
      const float* base = (ten == 0) ? q1 : (ten == 1) ? k1 : (ten == 2) ? v1
                         : (ten == 3) ? q2 : (ten == 4) ? k2 : v2;
      const float* src = base + ((long)l * 8 + h) * 32768 + (long)rt * 64 * 64;
      u16* dst = Wb + (long)ten * HT + (long)lslot * 262144 + (long)h * 32768 + rt * 64;
      wtile(src, 64, 64, dst, 512);
    } else if (t < 512) {   // Wo [512][512] -> [512][512]
      int v_ = t - 384, o = v_ >> 6, w = v_ & 63, rt = w >> 3, ct = w & 7;
      const float* src = (o ? o2 : o1) + (long)l * 262144 + (long)rt * 64 * 512 + ct * 64;
      u16* dst = Wb + (long)(6 + o) * HT + (long)lslot * 262144 + (long)ct * 64 * 512 + rt * 64;
      wtile(src, 512, 64, dst, 512);
    } else if (t < 768) {   // W1 [512][2048] -> [2048][512]
      int v_ = t - 512, rt = v_ >> 5, ct = v_ & 31;
      const float* src = w1 + (long)l * 1048576 + (long)rt * 64 * 2048 + ct * 64;
      u16* dst = Wb + 8 * HT + (long)lslot * 1048576 + (long)ct * 64 * 512 + rt * 64;
      wtile(src, 2048, 64, dst, 512);
    } else {                // W2 [2048][512] -> [512][2048]
      int v_ = t - 768, rt = v_ >> 3, ct = v_ & 7;
      const float* src = w2 + (long)l * 1048576 + (long)rt * 64 * 512 + ct * 64;
      u16* dst = Wb + 12 * HT + (long)lslot * 1048576 + (long)ct * 64 * 2048 + rt * 64;
      wtile(src, 512, 64, dst, 2048);
    }
  } else {                  // Wout [512][37000] -> [37120][512], zero-padded
    int v_ = u - layerBlocks;
    int rt = v_ & 7, ct = v_ >> 3;
    int c0 = ct * 64;
    int cv = Vc - c0; cv = cv < 0 ? 0 : (cv > 64 ? 64 : cv);
    const float* src = wout + (long)rt * 64 * Vc + c0;
    u16* dst = WoutT + (long)c0 * 512 + rt * 64;
    wtile(src, Vc, cv, dst, 512);
  }
}

// ============ gemm128: 128x128 tile, BK=64, bf16 in, global_load_lds staging ======
// A [M][K] bf16 row-major, Bt [Npad][K] bf16 row-major (B transposed). M%128==0.
// LDS fragment order: unit u = mi*128 + kg*16 + fr  <->  (row=mi*16+fr, k=kg*8..+7)
__global__ __launch_bounds__(256) void gemm128(
    const u16* __restrict__ A, const u16* __restrict__ Bt,
    const float* __restrict__ bias, void* __restrict__ Cv,
    int N, int K, int obf, int relu)
{
  __shared__ u16 smem[2 * 128 * 64];   // 32 KB : sA | sB
  u16* sA = smem;
  u16* sB = smem + 128 * 64;

  int tid = threadIdx.x, lane = tid & 63, wave = tid >> 6;
  int row0 = blockIdx.x * 128, col0 = blockIdx.y * 128;
  int frs = lane & 15, kq = lane >> 4;

  const u16* pA[4]; const u16* pB[4]; u16* lA[4]; u16* lB[4];
#pragma unroll
  for (int i = 0; i < 4; i++) {
    int idx = wave * 4 + i, mi = idx >> 1, kgh = idx & 1;
    pA[i] = A  + (long)(row0 + mi * 16 + frs) * K + kgh * 32 + kq * 8;
    pB[i] = Bt + (long)(col0 + mi * 16 + frs) * K + kgh * 32 + kq * 8;
    lA[i] = sA + (mi * 2 + kgh) * 512;
    lB[i] = sB + (mi * 2 + kgh) * 512;
  }

  f32x4 acc[4][4];
#pragma unroll
  for (int i = 0; i < 4; i++)
#pragma unroll
    for (int j = 0; j < 4; j++) acc[i][j] = (f32x4){0.f, 0.f, 0.f, 0.f};

  int m0 = (wave >> 1) * 64, n0 = (wave & 1) * 64;

  for (int kt = 0; kt < K; kt += 64) {
#pragma unroll
    for (int i = 0; i < 4; i++) { gload16(pA[i], lA[i]); pA[i] += 64; }
#pragma unroll
    for (int i = 0; i < 4; i++) { gload16(pB[i], lB[i]); pB[i] += 64; }
    __syncthreads();   // drains vmcnt -> LDS tiles visible
#pragma unroll
    for (int ks = 0; ks < 2; ks++) {
      bf16x8 af[4], bf[4];
#pragma unroll
      for (int i = 0; i < 4; i++) {
        af[i] = *(const bf16x8*)&sA[(((m0 >> 4) + i) * 128 + ks * 64 + lane) * 8];
        bf[i] = *(const bf16x8*)&sB[(((n0 >> 4) + i) * 128 + ks * 64 + lane) * 8];
      }
#pragma unroll
      for (int mi = 0; mi < 4; mi++)
#pragma unroll
        for (int ni = 0; ni < 4; ni++)
          acc[mi][ni] = __builtin_amdgcn_mfma_f32_16x16x32_bf16(af[mi], bf[ni], acc[mi][ni], 0, 0, 0);
    }
    __syncthreads();   // readers done before next overwrite
  }

  // LDS-bounce epilogue -> full-line coalesced stores (per-wave private scratch)
  float* scr = (float*)smem + wave * (16 * 68);
  int rg = kq * 4;
  u16* Cus = (u16*)Cv; float* Cf = (float*)Cv;
#pragma unroll
  for (int mi = 0; mi < 4; mi++) {
#pragma unroll
    for (int ni = 0; ni < 4; ni++) {
      int colg = col0 + n0 + ni * 16 + frs;
      float bv = bias ? ((colg < N) ? bias[colg] : 0.f) : 0.f;
#pragma unroll
      for (int j = 0; j < 4; j++) {
        float o = acc[mi][ni][j] + bv;
        if (relu) o = fmaxf(o, 0.f);
        scr[(rg + j) * 68 + ni * 16 + frs] = o;
      }
    }
    int rbase = row0 + m0 + mi * 16;
    if (obf) {
#pragma unroll
      for (int p = 0; p < 2; p++) {
        int rowl = p * 8 + (lane >> 3), c8 = (lane & 7) * 8;
        float4 v0 = *(const float4*)&scr[rowl * 68 + c8];
        float4 v1 = *(const float4*)&scr[rowl * 68 + c8 + 4];
        union { us8 v; u16 s[8]; } w;
        w.s[0] = f2bf(v0.x); w.s[1] = f2bf(v0.y); w.s[2] = f2bf(v0.z); w.s[3] = f2bf(v0.w);
        w.s[4] = f2bf(v1.x); w.s[5] = f2bf(v1.y); w.s[6] = f2bf(v1.z); w.s[7] = f2bf(v1.w);
        *(us8*)&Cus[(long)(rbase + rowl) * N + col0 + n0 + c8] = w.v;
      }
    } else {
#pragma unroll
      for (int p = 0; p < 4; p++) {
        int rowl = p * 4 + kq, c4 = frs * 4;
        int colg = col0 + n0 + c4;
        float4 v = *(const float4*)&scr[rowl * 68 + c4];
        if (colg < N)
          *(float4*)&Cf[(long)(rbase + rowl) * N + colg] = v;
      }
    }
  }
}

// ============ gemm64: 64x64 tile, BK=64, bf16 in, global_load_lds staging =========
// modes: 0 plain batched | 1 fused QK (z=t*32+zz; A-src t?A2:A; Bt + t*tQK + h*btB)
//        2 V^T (A=WvT + (z&7)*aB, Bt + (z>>3)*btB) | 3 PV+concat (C: cc layout)
__global__ __launch_bounds__(256) void gemm64(
    const u16* __restrict__ A, const u16* __restrict__ A2,
    const u16* __restrict__ Bt, const float* __restrict__ bias, void* __restrict__ Cv,
    int N, int K, int lda, long aB, long btB, long cB, long tQK, int mode, int obf)
{
  int z = blockIdx.z;
  const u16* Ap; const u16* Btp; long coff; int ldc;
  if (mode == 1) {
    int t = z >> 5, zz = z & 31;
    Ap = (t == 0 ? A : A2) + (long)(zz >> 3) * aB;
    Btp = Bt + (long)t * tQK + (long)(zz & 7) * btB;
    coff = (long)z * cB; ldc = N;
  } else if (mode == 2) {
    Ap = A + (long)(z & 7) * aB;
    Btp = Bt + (long)(z >> 3) * btB;
    coff = (long)z * cB; ldc = N;
  } else if (mode == 3) {
    Ap = A + (long)z * aB;
    Btp = Bt + (long)z * btB;
    coff = (long)(z >> 3) * (512 * 512) + (long)(z & 7) * 64; ldc = 512;
  } else {
    Ap = A + (long)z * aB;
    Btp = Bt + (long)z * btB;
    coff = (long)z * cB; ldc = N;
  }

  __shared__ u16 smem[2 * 64 * 64];  // 16 KB
  u16* sA = smem; u16* sB = smem + 4096;

  int tid = threadIdx.x, lane = tid & 63, wave = tid >> 6;
  int row0 = blockIdx.x * 64, col0 = blockIdx.y * 64;
  int frs = lane & 15, kq = lane >> 4;

  const u16* pA[2]; const u16* pB[2]; u16* lA[2]; u16* lB[2];
#pragma unroll
  for (int i = 0; i < 2; i++) {
    pA[i] = Ap  + (long)(row0 + wave * 16 + frs) * lda + i * 32 + kq * 8;
    pB[i] = Btp + (long)(col0 + wave * 16 + frs) * K   + i * 32 + kq * 8;
    lA[i] = sA + (wave * 2 + i) * 512;
    lB[i] = sB + (wave * 2 + i) * 512;
  }

  f32x4 acc[2][2];
  acc[0][0] = acc[0][1] = acc[1][0] = acc[1][1] = (f32x4){0.f, 0.f, 0.f, 0.f};
  int m0 = (wave >> 1) * 32, n0 = (wave & 1) * 32;

  for (int kt = 0; kt < K; kt += 64) {
#pragma unroll
    for (int i = 0; i < 2; i++) {
      gload16(pA[i], lA[i]); pA[i] += 64;
      gload16(pB[i], lB[i]); pB[i] += 64;
    }
    __syncthreads();
    bf16x8 af[2][2], bf[2][2];
#pragma unroll
    for (int i = 0; i < 2; i++)
#pragma unroll
      for (int ks = 0; ks < 2; ks++) {
        af[i][ks] = *(const bf16x8*)&sA[(((m0 >> 4) + i) * 128 + ks * 64 + lane) * 8];
        bf[i][ks] = *(const bf16x8*)&sB[(((n0 >> 4) + i) * 128 + ks * 64 + lane) * 8];
      }
#pragma unroll
    for (int ks = 0; ks < 2; ks++)
#pragma unroll
      for (int mi = 0; mi < 2; mi++)
#pragma unroll
        for (int ni = 0; ni < 2; ni++)
          acc[mi][ni] = __builtin_amdgcn_mfma_f32_16x16x32_bf16(af[mi][ks], bf[ni][ks], acc[mi][ni], 0, 0, 0);
    __syncthreads();
  }

  int rg = kq * 4;
  u16* Cus = (u16*)Cv + coff; float* Cf = (float*)Cv + coff;
#pragma unroll
  for (int ni = 0; ni < 2; ni++) {
    int col = col0 + n0 + ni * 16 + frs;
    float bv = bias ? bias[col] : 0.f;
#pragma unroll
    for (int mi = 0; mi < 2; mi++) {
      int r0 = row0 + m0 + mi * 16 + rg;
#pragma unroll
      for (int j = 0; j < 4; j++) {
        float o = acc[mi][ni][j] + bv;
        if (obf) Cus[(long)(r0 + j) * ldc + col] = f2bf(o);
        else     Cf [(long)(r0 + j) * ldc + col] = o;
      }
    }
  }
}

// ---------------- NT: scores = alpha * Q @ K^T (bf16 in, fp32 out) ------------
__global__ __launch_bounds__(256) void gemm_nt_mfma(
    const u16* __restrict__ A, const u16* __restrict__ Bm, float* __restrict__ C,
    long aB, long bB, long cB, float alpha, int causal)
{
  if (causal && blockIdx.y > blockIdx.x) return;   // tile entirely above diagonal
  int z = blockIdx.z;
  const u16* Ap = A + (long)z * aB;
  const u16* Bp = Bm + (long)z * bB;
  float* Cp = C + (long)z * cB;

  int tid = threadIdx.x, lane = tid & 63, wave = tid >> 6;
  int m0 = blockIdx.x * 128 + (wave >> 1) * 64;
  int n0 = blockIdx.y * 128 + (wave & 1) * 64;
  int fr = lane & 15, fk = (lane >> 4) * 8;

  bf16x8 af[4][2];
#pragma unroll
  for (int mi = 0; mi < 4; mi++) {
    const u16* p = Ap + (long)(m0 + mi * 16 + fr) * DKc + fk;
    af[mi][0] = *(const bf16x8*)p;
    af[mi][1] = *(const bf16x8*)(p + 32);
  }

  f32x4 acc[4][4];
#pragma unroll
  for (int i = 0; i < 4; i++)
#pragma unroll
    for (int j = 0; j < 4; j++) acc[i][j] = (f32x4){0.f, 0.f, 0.f, 0.f};

#pragma unroll
  for (int ni = 0; ni < 4; ni++) {
    const u16* q = Bp + (long)(n0 + ni * 16 + fr) * DKc + fk;
    bf16x8 b0 = *(const bf16x8*)q;
    bf16x8 b1 = *(const bf16x8*)(q + 32);
#pragma unroll
    for (int mi = 0; mi < 4; mi++) {
      acc[mi][ni] = __builtin_amdgcn_mfma_f32_16x16x32_bf16(af[mi][0], b0, acc[mi][ni], 0, 0, 0);
      acc[mi][ni] = __builtin_amdgcn_mfma_f32_16x16x32_bf16(af[mi][1], b1, acc[mi][ni], 0, 0, 0);
    }
  }

  int rg = (lane >> 4) << 2;
#pragma unroll
  for (int ni = 0; ni < 4; ni++) {
    int col = n0 + ni * 16 + fr;
#pragma unroll
    for (int mi = 0; mi < 4; mi++) {
      int r0 = m0 + mi * 16 + rg;
#pragma unroll
      for (int j = 0; j < 4; j++)
        Cp[(long)(r0 + j) * Sc + col] = acc[mi][ni][j] * alpha;
    }
  }
}

// ------- attention softmax: fp32 scores in, bf16 probs written in-place -------
// probs row r occupies the first 1024 B of scores row r (row stride 1024 u16).
__global__ __launch_bounds__(256) void attn_softmax(float* __restrict__ sc, int causal) {
  int row = blockIdx.x;                 // (b*H+h)*S + s
  int s = row & (Sc - 1);
  float* p = sc + (long)row * Sc;
  u16* pb = (u16*)p;
  int t0 = threadIdx.x, t1 = threadIdx.x + 256;
  int limit = causal ? (s + 1) : Sc;

  float v0 = (t0 < limit) ? p[t0] : NEG_INF;
  float v1 = (t1 < limit) ? p[t1] : NEG_INF;
  float mx = fmaxf(v0, v1);
  __shared__ float sm[4], sm2[4];
#pragma unroll
  for (int o = 32; o > 0; o >>= 1) mx = fmaxf(mx, __shfl_down(mx, o, 64));
  if ((threadIdx.x & 63) == 0) sm[threadIdx.x >> 6] = mx;
  __syncthreads();
  mx = fmaxf(fmaxf(sm[0], sm[1]), fmaxf(sm[2], sm[3]));

  float e0 = (t0 < limit) ? __expf(v0 - mx) : 0.f;
  float e1 = (t1 < limit) ? __expf(v1 - mx) : 0.f;
  float sum = e0 + e1;
#pragma unroll
  for (int o = 32; o > 0; o >>= 1) sum += __shfl_down(sum, o, 64);
  if ((threadIdx.x & 63) == 0) sm2[threadIdx.x >> 6] = sum;
  __syncthreads();
  sum = sm2[0] + sm2[1] + sm2[2] + sm2[3];
  float inv = 1.f / sum;
  pb[t0] = f2bf(e0 * inv);
  pb[t1] = f2bf(e1 * inv);
}

// -------- fused residual add + BN partial stats (deterministic) --------
__global__ __launch_bounds__(256) void add_stats(
    float* __restrict__ x, const float* __restrict__ y, float* __restrict__ part)
{
  int blk = blockIdx.x;
  int c = threadIdx.x * 2;
  int r0 = blk * 16;
  float s0 = 0.f, s1 = 0.f, q0 = 0.f, q1 = 0.f;
#pragma unroll 4
  for (int r = r0; r < r0 + 16; r++) {
    long off = (long)r * Dc + c;
    float2 v = *(const float2*)&x[off];
    float2 w = *(const float2*)&y[off];
    v.x += w.x; v.y += w.y;
    *(float2*)&x[off] = v;
    s0 += v.x; q0 += v.x * v.x;
    s1 += v.y; q1 += v.y * v.y;
  }
  part[(long)c * 128 + blk] = s0;
  part[(long)(c + 1) * 128 + blk] = s1;
  part[Dc * 128 + (long)c * 128 + blk] = q0;
  part[Dc * 128 + (long)(c + 1) * 128 + blk] = q1;
}

__global__ __launch_bounds__(256) void bn_finalize(
    const float* __restrict__ part, const float* __restrict__ g,
    const float* __restrict__ b, float* __restrict__ scale, float* __restrict__ shift)
{
  int c = blockIdx.x * 256 + threadIdx.x;
  if (c >= Dc) return;
  const float* ps = part + (long)c * 128;
  const float* pq = part + Dc * 128 + (long)c * 128;
  float s = 0.f, q = 0.f;
#pragma unroll 8
  for (int i = 0; i < 128; i++) { s += ps[i]; q += pq[i]; }
  float mu  = s * (1.f / Mc);
  float var = q * (1.f / Mc) - mu * mu;
  float sc = g[c] * rsqrtf(var + BN_EPS);
  scale[c] = sc;
  shift[c] = b[c] - mu * sc;
}

__global__ void bn_apply(float* __restrict__ x, u16* __restrict__ xh,
                         const float* __restrict__ scale, const float* __restrict__ shift) {
  int i = blockIdx.x * blockDim.x + threadIdx.x;
  if (i >= Mc * Dc) return;
  int c = i & 511;
  float v = x[i] * scale[c] + shift[c];
  x[i] = v;
  xh[i] = f2bf(v);
}

// ---------------- vocab softmax ------------
static constexpr int VT = 37;  // ceil(37000/1024)
__global__ __launch_bounds__(1024) void vocab_softmax(float* __restrict__ out) {
  long row = blockIdx.x;
  float* p = out + row * (long)Vc;
  float v[VT];
  float mx = NEG_INF;
#pragma unroll
  for (int j = 0; j < VT; j++) {
    int c = threadIdx.x + j * 1024;
    v[j] = (c < Vc) ? p[c] : NEG_INF;
    mx = fmaxf(mx, v[j]);
  }
  __shared__ float sm[16], sm2[16];
#pragma unroll
  for (int o = 32; o > 0; o >>= 1) mx = fmaxf(mx, __shfl_down(mx, o, 64));
  if ((threadIdx.x & 63) == 0) sm[threadIdx.x >> 6] = mx;
  __syncthreads();
  float m2 = sm[0];
#pragma unroll
  for (int i = 1; i < 16; i++) m2 = fmaxf(m2, sm[i]);
  mx = m2;

  float sum = 0.f;
#pragma unroll
  for (int j = 0; j < VT; j++) {
    int c = threadIdx.x + j * 1024;
    float e = (c < Vc) ? __expf(v[j] - mx) : 0.f;
    v[j] = e; sum += e;
  }
#pragma unroll
  for (int o = 32; o > 0; o >>= 1) sum += __shfl_down(sum, o, 64);
  if ((threadIdx.x & 63) == 0) sm2[threadIdx.x >> 6] = sum;
  __syncthreads();
  float s2 = 0.f;
#pragma unroll
  for (int i = 0; i < 16; i++) s2 += sm2[i];
  float inv = 1.f / s2;
#pragma unroll
  for (int j = 0; j < VT; j++) {
    int c = threadIdx.x + j * 1024;
    if (c < Vc) p[c] = v[j] * inv;
  }
}

// ---------------- orchestration ----------------
extern "C" void kernel_launch(void* const* d_in, const int* in_sizes, int n_in,
                              void* d_out, int out_size, void* d_ws, size_t ws_size,
                              hipStream_t stream) {
  const int*   idx   = (const int*)d_in[0];
  const float* enc   = (const float*)d_in[1];
  const float* emb   = (const float*)d_in[2];
  const float* Wq1   = (const float*)d_in[3];
  const float* Wk1   = (const float*)d_in[4];
  const float* Wv1   = (const float*)d_in[5];
  const float* Wo1   = (const float*)d_in[6];
  const float* Wq2   = (const float*)d_in[7];
  const float* Wk2   = (const float*)d_in[8];
  const float* Wv2   = (const float*)d_in[9];
  const float* Wo2   = (const float*)d_in[10];
  const float* gamma = (const float*)d_in[11];
  const float* beta  = (const float*)d_in[12];
  const float* W1    = (const float*)d_in[13];
  const float* b1    = (const float*)d_in[14];
  const float* W2    = (const float*)d_in[15];
  const float* b2    = (const float*)d_in[16];
  const float* Wout  = (const float*)d_in[17];
  const float* bout  = (const float*)d_in[18];
  float* out = (float*)d_out;

  // ---- workspace layout (float units) ----
  float* ws = (float*)d_ws;
  size_t off = 0;
  float* x      = ws + off; off += 1048576;
  float* t0     = ws + off; off += 1048576;
  u16*   xh     = (u16*)(ws + off); off += 524288;
  u16*   Q      = (u16*)(ws + off); off += 524288;   // Q then K contiguous (mode-1 C stride)
  u16*   Kb     = (u16*)(ws + off); off += 524288;
  u16*   Vt     = (u16*)(ws + off); off += 524288;
  u16*   cc     = (u16*)(ws + off); off += 524288;
  u16*   ench   = (u16*)(ws + off); off += 524288;
  float* part   = ws + off; off += 131072;
  float* scalep = ws + off; off += 512;
  float* shiftp = ws + off; off += 512;
  float* scores = ws + off; off += 8388608;          // probs (bf16) live in-place; ff1h overlays
  u16*   Wb     = (u16*)(ws + off);

  const bool upfront = ws_size >= (off + 22085632 + 8192) * 4;
  const long HTe = (long)(upfront ? 6 : 1) * 262144;
  u16* WoutT = upfront ? (Wb + 16 * HTe) : (u16*)scores;   // per-layer: built at the end over scores+Wb
  u16* ff1h  = (u16*)scores;

  const int n1 = Mc * Dc;
  const int eb = (n1 + 255) / 256;

  // enc -> bf16 (once)
  cvt_bf16<<<1024, 256, 0, stream>>>(enc, ench, 262144);
  if (upfront)
    wconv<<<6 * 1024 + 4640, 256, 0, stream>>>(Wq1, Wk1, Wv1, Wo1, Wq2, Wk2, Wv2, Wo2,
                                               W1, W2, Wout, Wb, WoutT, 6, 0);
  embed_k<<<eb, 256, 0, stream>>>(idx, emb, x, xh);

  for (int l = 0; l < NXc; l++) {
    if (!upfront)
      wconv<<<1024, 256, 0, stream>>>(Wq1, Wk1, Wv1, Wo1, Wq2, Wk2, Wv2, Wo2,
                                      W1, W2, Wout, Wb, WoutT, 1, l);
    const long lsl = upfront ? (long)l : 0;
    const u16* WqT1l = Wb + 0 * HTe + lsl * 262144;
    const u16* WvT1l = Wb + 2 * HTe + lsl * 262144;
    const u16* WqT2l = Wb + 3 * HTe + lsl * 262144;
    const u16* WvT2l = Wb + 5 * HTe + lsl * 262144;
    const u16* WoT1l = Wb + 6 * HTe + lsl * 262144;
    const u16* WoT2l = Wb + 7 * HTe + lsl * 262144;
    const u16* W1Tl  = Wb + 8 * HTe + lsl * 1048576;
    const u16* W2Tl  = Wb + 12 * HTe + lsl * 1048576;

    // ======== self-attention (causal) ========
    {
      gemm64<<<dim3(8, 1, 64), 256, 0, stream>>>(   // Q,K fused
          xh, xh, WqT1l, nullptr, Q, 64, 512, 512, 262144, 32768, 32768, HTe, 1, 1);
      gemm64<<<dim3(1, 8, 32), 256, 0, stream>>>(   // V^T = Wv^T x^T
          WvT1l, nullptr, xh, nullptr, Vt, 512, 512, 512, 32768, 262144, 32768, 0, 2, 1);
      gemm_nt_mfma<<<dim3(4, 4, 32), 256, 0, stream>>>(Q, Kb, scores, 32768, 32768, 262144, 0.125f, 1);
      attn_softmax<<<Bc * Hc * Sc, 256, 0, stream>>>(scores, 1);
      gemm64<<<dim3(8, 1, 32), 256, 0, stream>>>(   // PV + concat -> cc (bf16)
          (u16*)scores, nullptr, Vt, nullptr, cc, 64, 512, 1024, 524288, 32768, 0, 0, 3, 1);
      gemm64<<<dim3(32, 8, 1), 256, 0, stream>>>(   // Wo
          cc, nullptr, WoT1l, nullptr, t0, 512, 512, 512, 0, 0, 0, 0, 0, 0);
      add_stats<<<128, 256, 0, stream>>>(x, t0, part);
      bn_finalize<<<2, 256, 0, stream>>>(part, gamma + (long)(l * 3 + 0) * Dc, beta + (long)(l * 3 + 0) * Dc, scalep, shiftp);
      bn_apply<<<eb, 256, 0, stream>>>(x, xh, scalep, shiftp);
    }
    // ======== cross-attention ========
    {
      gemm64<<<dim3(8, 1, 64), 256, 0, stream>>>(
          xh, ench, WqT2l, nullptr, Q, 64, 512, 512, 262144, 32768, 32768, HTe, 1, 1);
      gemm64<<<dim3(1, 8, 32), 256, 0, stream>>>(
          WvT2l, nullptr, ench, nullptr, Vt, 512, 512, 512, 32768, 262144, 32768, 0, 2, 1);
      gemm_nt_mfma<<<dim3(4, 4, 32), 256, 0, stream>>>(Q, Kb, scores, 32768, 32768, 262144, 0.125f, 0);
      attn_softmax<<<Bc * Hc * Sc, 256, 0, stream>>>(scores, 0);
      gemm64<<<dim3(8, 1, 32), 256, 0, stream>>>(
          (u16*)scores, nullptr, Vt, nullptr, cc, 64, 512, 1024, 524288, 32768, 0, 0, 3, 1);
      gemm64<<<dim3(32, 8, 1), 256, 0, stream>>>(
          cc, nullptr, WoT2l, nullptr, t0, 512, 512, 512, 0, 0, 0, 0, 0, 0);
      add_stats<<<128, 256, 0, stream>>>(x, t0, part);
      bn_finalize<<<2, 256, 0, stream>>>(part, gamma + (long)(l * 3 + 1) * Dc, beta + (long)(l * 3 + 1) * Dc, scalep, shiftp);
      bn_apply<<<eb, 256, 0, stream>>>(x, xh, scalep, shiftp);
    }
    // ======== FFN ========
    {
      gemm128<<<dim3(16, 16), 256, 0, stream>>>(xh, W1Tl, b1 + (long)l * DFFc, ff1h, 2048, 512, 1, 1);
      gemm64<<<dim3(32, 8, 1), 256, 0, stream>>>(
          ff1h, nullptr, W2Tl, b2 + (long)l * Dc, t0, 512, 2048, 2048, 0, 0, 0, 0, 0, 0);
      add_stats<<<128, 256, 0, stream>>>(x, t0, part);
      bn_finalize<<<2, 256, 0, stream>>>(part, gamma + (long)(l * 3 + 2) * Dc, beta + (long)(l * 3 + 2) * Dc, scalep, shiftp);
      bn_apply<<<eb, 256, 0, stream>>>(x, xh, scalep, shiftp);
    }
  }

  // ======== final projection + vocab softmax ========
  if (!upfront)   // build Wout^T now (overlays scores/Wb region, both free)
    wconv<<<4640, 256, 0, stream>>>(Wq1, Wk1, Wv1, Wo1, Wq2, Wk2, Wv2, Wo2,
                                    W1, W2, Wout, Wb, WoutT, 0, 0);
  gemm128<<<dim3(16, 290), 256, 0, stream>>>(xh, WoutT, bout, out, Vc, 512, 0, 0);
  vocab_softmax<<<Mc, 1024, 0, stream>>>(out);
}